// Round 1
// baseline (896.334 us; speedup 1.0000x reference)
//
#include <hip/hip_runtime.h>

// SpatialHRVQTokenizer: 3-level VQ forward.
// Inputs (fp32): l0 (8192,4,384), l1 (8192,16,384), l2 (8192,16,384),
//                cb0/1/2 (256,384).
// Output (flat fp32, concatenated):
//   idx0 [0,32768)  idx1 [32768,163840)  idx2 [163840,294912)
//   loss [294912]
//   q0   [294913, 12877825)  q1 [12877825, 63209473)  q2 [63209473, 113541121)

#define D_MODEL 384
#define NCODES  256
#define MT      64   // rows (vectors) per block
#define KC      32   // K chunk staged in LDS
#define PITCH   36   // LDS row pitch (floats): 16B-aligned, stride-4 banks

// ---------------- code norms ‖e‖² ----------------
__global__ __launch_bounds__(64) void vq_norms(const float* __restrict__ c0,
                                               const float* __restrict__ c1,
                                               const float* __restrict__ c2,
                                               float* __restrict__ en) {
  const int row = blockIdx.x;                 // 0..767
  const float* cb = (row < 256) ? c0 : ((row < 512) ? c1 : c2);
  const int n = row & 255;
  const int lane = threadIdx.x;
  const float* r = cb + (size_t)n * D_MODEL;
  float s = 0.f;
  for (int c = lane; c < D_MODEL; c += 64) s = fmaf(r[c], r[c], s);
  for (int m = 1; m < 64; m <<= 1) s += __shfl_xor(s, m, 64);
  if (lane == 0) en[row] = s;
}

// ---------------- main fused VQ kernel ----------------
// One block: 64 vectors x all 256 codes. Thread (tr=tid>>5, tc=tid&31)
// owns rows m = tr + 8i (i<8) and codes n = tc + 32j (j<8).
__global__ __launch_bounds__(256) void vq_main(const float* __restrict__ x,
                                               const float* __restrict__ cb,
                                               const float* __restrict__ en,
                                               float* __restrict__ out_idx,
                                               float* __restrict__ out_q,
                                               float* __restrict__ loss_part) {
  __shared__ float xs[MT][PITCH];       // 9216 B
  __shared__ float es[NCODES][PITCH];   // 36864 B
  __shared__ float xnp[MT][4];
  __shared__ float xns[MT];
  __shared__ int   idxs[MT];
  __shared__ float dmins[MT];

  const int tid = threadIdx.x;
  const int tc = tid & 31;
  const int tr = tid >> 5;
  const long m0 = (long)blockIdx.x * MT;
  const int lr = tid >> 2;            // staging row 0..63
  const int lc = (tid & 3) << 3;      // staging col offset {0,8,16,24}

  float acc[8][8];
#pragma unroll
  for (int i = 0; i < 8; ++i)
#pragma unroll
    for (int j = 0; j < 8; ++j) acc[i][j] = 0.f;
  float xn_part = 0.f;

  const float* xrow = x + (m0 + lr) * (long)D_MODEL + lc;
  const float* crow = cb + (size_t)lr * D_MODEL + lc;

  for (int k0 = 0; k0 < D_MODEL; k0 += KC) {
    // stage x chunk (and accumulate row-norm partial for free)
    float4 a0 = *(const float4*)(xrow + k0);
    float4 a1 = *(const float4*)(xrow + k0 + 4);
    xn_part = fmaf(a0.x, a0.x, xn_part); xn_part = fmaf(a0.y, a0.y, xn_part);
    xn_part = fmaf(a0.z, a0.z, xn_part); xn_part = fmaf(a0.w, a0.w, xn_part);
    xn_part = fmaf(a1.x, a1.x, xn_part); xn_part = fmaf(a1.y, a1.y, xn_part);
    xn_part = fmaf(a1.z, a1.z, xn_part); xn_part = fmaf(a1.w, a1.w, xn_part);
    *(float4*)&xs[lr][lc]     = a0;
    *(float4*)&xs[lr][lc + 4] = a1;
    // stage codebook chunk: rows lr, lr+64, lr+128, lr+192
#pragma unroll
    for (int p = 0; p < 4; ++p) {
      const int n = lr + (p << 6);
      float4 b0 = *(const float4*)(crow + (size_t)(p << 6) * D_MODEL + k0);
      float4 b1 = *(const float4*)(crow + (size_t)(p << 6) * D_MODEL + k0 + 4);
      *(float4*)&es[n][lc]     = b0;
      *(float4*)&es[n][lc + 4] = b1;
    }
    __syncthreads();

#pragma unroll
    for (int k4 = 0; k4 < KC; k4 += 4) {
      float4 xf[8];
#pragma unroll
      for (int i = 0; i < 8; ++i) xf[i] = *(const float4*)&xs[tr + (i << 3)][k4];
#pragma unroll
      for (int j = 0; j < 8; ++j) {
        float4 ef = *(const float4*)&es[tc + (j << 5)][k4];
#pragma unroll
        for (int i = 0; i < 8; ++i) {
          acc[i][j] = fmaf(xf[i].x, ef.x, acc[i][j]);
          acc[i][j] = fmaf(xf[i].y, ef.y, acc[i][j]);
          acc[i][j] = fmaf(xf[i].z, ef.z, acc[i][j]);
          acc[i][j] = fmaf(xf[i].w, ef.w, acc[i][j]);
        }
      }
    }
    __syncthreads();
  }

  // row norms: combine 4 partials per row
  xnp[lr][tid & 3] = xn_part;
  __syncthreads();
  if (tid < MT) xns[tid] = (xnp[tid][0] + xnp[tid][1]) + (xnp[tid][2] + xnp[tid][3]);
  __syncthreads();

  // code-norm fragment (L2-hot)
  float enf[8];
#pragma unroll
  for (int j = 0; j < 8; ++j) enf[j] = en[tc + (j << 5)];

  // d2 = (xn - 2*dot) + en ; argmin with first-occurrence tie-break
#pragma unroll
  for (int i = 0; i < 8; ++i) {
    const int m = tr + (i << 3);
    const float xn = xns[m];
    float best = 3.4e38f; int bidx = 0;
#pragma unroll
    for (int j = 0; j < 8; ++j) {           // j ascending => n ascending
      float d = fmaf(-2.f, acc[i][j], xn) + enf[j];
      const int n = tc + (j << 5);
      if (d < best) { best = d; bidx = n; }
    }
    for (int mm = 1; mm < 32; mm <<= 1) {   // reduce across the 32 code-lanes
      float ov = __shfl_xor(best, mm, 64);
      int   oi = __shfl_xor(bidx, mm, 64);
      if (ov < best || (ov == best && oi < bidx)) { best = ov; bidx = oi; }
    }
    if (tc == 0) {
      idxs[m]  = bidx;
      dmins[m] = best;
      out_idx[m0 + m] = (float)bidx;
    }
  }
  __syncthreads();

  // gather q = codebook[idx] (coalesced stores; codebook rows are L2-hot)
  float* qb = out_q + m0 * (long)D_MODEL;
  for (int g = tid; g < MT * D_MODEL; g += 256) {
    const int m = g / D_MODEL;
    const int c = g - m * D_MODEL;
    qb[g] = cb[(size_t)idxs[m] * D_MODEL + c];
  }

  // deterministic per-block loss partial (sum of d2_min over 64 rows)
  if (tid < 64) {
    float s = dmins[tid];
    for (int mm = 1; mm < 64; mm <<= 1) s += __shfl_xor(s, mm, 64);
    if (tid == 0) loss_part[blockIdx.x] = s;
  }
}

// ---------------- deterministic final loss reduce ----------------
__global__ __launch_bounds__(256) void vq_finalize(const float* __restrict__ lp,
                                                   float* __restrict__ out_loss) {
  const int tid = threadIdx.x;
  double s0 = 0.0, s1 = 0.0, s2 = 0.0;
  for (int i = tid; i < 512;  i += 256) s0 += (double)lp[i];
  for (int i = tid; i < 2048; i += 256) s1 += (double)lp[512 + i];
  for (int i = tid; i < 2048; i += 256) s2 += (double)lp[2560 + i];
  __shared__ double sh[256];
  sh[tid] = s0 * (0.05 / (32768.0 * 384.0))
          + s1 * (0.25 / (131072.0 * 384.0))
          + s2 * (0.60 / (131072.0 * 384.0));
  __syncthreads();
  for (int s = 128; s > 0; s >>= 1) {
    if (tid < s) sh[tid] += sh[tid + s];
    __syncthreads();
  }
  if (tid == 0) out_loss[0] = (float)sh[0];
}

extern "C" void kernel_launch(void* const* d_in, const int* in_sizes, int n_in,
                              void* d_out, int out_size, void* d_ws, size_t ws_size,
                              hipStream_t stream) {
  const float* l0 = (const float*)d_in[0];
  const float* l1 = (const float*)d_in[1];
  const float* l2 = (const float*)d_in[2];
  const float* c0 = (const float*)d_in[3];
  const float* c1 = (const float*)d_in[4];
  const float* c2 = (const float*)d_in[5];
  float* out = (float*)d_out;
  float* en  = (float*)d_ws;   // 768 floats: code norms
  float* lp  = en + 768;       // 4608 floats: per-block loss partials

  vq_norms<<<768, 64, 0, stream>>>(c0, c1, c2, en);

  // level 0: 32768 vectors -> 512 blocks
  vq_main<<<512, 256, 0, stream>>>(l0, c0, en,
                                   out + 0, out + 294913, lp);
  // level 1: 131072 vectors -> 2048 blocks
  vq_main<<<2048, 256, 0, stream>>>(l1, c1, en + 256,
                                    out + 32768, out + 12877825, lp + 512);
  // level 2: 131072 vectors -> 2048 blocks
  vq_main<<<2048, 256, 0, stream>>>(l2, c2, en + 512,
                                    out + 163840, out + 63209473, lp + 2560);

  vq_finalize<<<1, 256, 0, stream>>>(lp, out + 294912);
}

// Round 3
// 580.305 us; speedup vs baseline: 1.5446x; 1.5446x over previous
//
#include <hip/hip_runtime.h>

// SpatialHRVQTokenizer: 3-level VQ forward via f16-split MFMA GEMM + exact rescue.
// d2 = ||x||^2 - 2 x.e + ||e||^2 ; argmin (first-index ties) + q gather + loss.
// Output (flat fp32): idx0[0,32768) idx1[...,163840) idx2[...,294912)
//   loss[294912]  q0[294913..)  q1[12877825..)  q2[63209473..)
//
// ws layout (float units):
//   [0..4)        counts (int, per level)
//   [4..772)      en: code norms (768)
//   [772..295684)     dmin_all (294912)
//   [295684..590596)  xn_all   (294912)
//   [590596..623364)  list0 (cap 32768)
//   [623364..754436)  list1 (cap 131072)
//   [754436..885508)  list2 (cap 131072)
//   [885508..886660)  lp (576 doubles)   total ~3.55 MB

typedef _Float16 half8 __attribute__((ext_vector_type(8)));
typedef float f32x16 __attribute__((ext_vector_type(16)));

#define D_MODEL 384
#define NSEG 96
#define NKT 12
#define BM 64
#define RTAU 0.004f

__device__ __forceinline__ float4 ld4(const float* p) { return *(const float4*)p; }

__device__ __forceinline__ void cvt8(const float4& a, const float4& b, half8& hi, half8& lo) {
  const float v[8] = {a.x, a.y, a.z, a.w, b.x, b.y, b.z, b.w};
#pragma unroll
  for (int u = 0; u < 8; ++u) {
    _Float16 h = (_Float16)v[u];
    hi[u] = h;
    lo[u] = (_Float16)(v[u] - (float)h);
  }
}

// ---------------- code norms + counter zeroing ----------------
__global__ __launch_bounds__(64) void vq_norms(const float* __restrict__ c0,
                                               const float* __restrict__ c1,
                                               const float* __restrict__ c2,
                                               float* __restrict__ en,
                                               int* __restrict__ counts) {
  if (blockIdx.x == 0 && threadIdx.x < 4) counts[threadIdx.x] = 0;
  const int row = blockIdx.x;  // 0..767
  const float* cb = (row < 256) ? c0 : ((row < 512) ? c1 : c2);
  const int n = row & 255;
  const int lane = threadIdx.x;
  const float* r = cb + (size_t)n * D_MODEL;
  float s = 0.f;
  for (int c = lane; c < D_MODEL; c += 64) s = fmaf(r[c], r[c], s);
  for (int m = 1; m < 64; m <<= 1) s += __shfl_xor(s, m, 64);
  if (lane == 0) en[row] = s;
}

// ---------------- main fused VQ kernel (MFMA) ----------------
// 256 threads = 4 waves (2M x 2N). BM=64 rows x 256 codes, BK=32.
__global__ __launch_bounds__(256) void vq_mfma(const float* __restrict__ x,
                                               const float* __restrict__ cb,
                                               const float* __restrict__ en,
                                               float* __restrict__ out_idx,
                                               float* __restrict__ out_q,
                                               float* __restrict__ dmin_lvl,
                                               float* __restrict__ xn_lvl,
                                               int* __restrict__ list,
                                               int* __restrict__ cnt) {
  __shared__ __align__(16) unsigned char smem[40960];
  half8* Ah = (half8*)smem;                 //  4 KB
  half8* Al = (half8*)(smem + 4096);        //  4 KB
  half8* Bh = (half8*)(smem + 8192);        // 16 KB
  half8* Bl = (half8*)(smem + 24576);       // 16 KB
  float* scanbuf = (float*)smem;            // [32][256] fp32, aliased post-K-loop
  __shared__ float en_s[256];
  __shared__ float4 red[32][8];
  __shared__ float4 rowres[BM];
  __shared__ float xnp[BM][4];
  __shared__ int   idxs[BM];

  const int tid = threadIdx.x;
  const int lane = tid & 63;
  const int w = tid >> 6, wm = w >> 1, wn = w & 1;
  const int c31 = lane & 31, h = lane >> 5;
  const long m0 = (long)blockIdx.x * BM;

  en_s[tid] = en[tid];

  const int amt = tid >> 7;
  const int akc = (tid >> 6) & 1;
  const float* ap = x + (m0 + amt * 32 + c31) * (long)D_MODEL + akc * 16 + h * 8;
  const int bg = tid >> 6;
  const float* bp0 = cb + (((bg * 2 + 0) * 32 + c31)) * (long)D_MODEL + h * 8;
  const float* bp1 = cb + (((bg * 2 + 1) * 32 + c31)) * (long)D_MODEL + h * 8;

  const int aidx = (amt * 2 + akc) * 64 + lane;
  const int bf00 = ((bg * 2 + 0) * 2 + 0) * 64 + lane;
  const int bf01 = ((bg * 2 + 0) * 2 + 1) * 64 + lane;
  const int bf10 = ((bg * 2 + 1) * 2 + 0) * 64 + lane;
  const int bf11 = ((bg * 2 + 1) * 2 + 1) * 64 + lane;

  float4 ra0, ra1, rb[8];
  ra0 = ld4(ap + 0);      ra1 = ld4(ap + 4);
  rb[0] = ld4(bp0 + 0);   rb[1] = ld4(bp0 + 4);
  rb[2] = ld4(bp0 + 16);  rb[3] = ld4(bp0 + 20);
  rb[4] = ld4(bp1 + 0);   rb[5] = ld4(bp1 + 4);
  rb[6] = ld4(bp1 + 16);  rb[7] = ld4(bp1 + 20);

  f32x16 acc[4];
#pragma unroll
  for (int n = 0; n < 4; ++n)
#pragma unroll
    for (int i = 0; i < 16; ++i) acc[n][i] = 0.f;

  float xn_part = 0.f;

  for (int kt = 0; kt < NKT; ++kt) {
    {
      half8 hv, lv;
      cvt8(ra0, ra1, hv, lv);
      xn_part = fmaf(ra0.x, ra0.x, xn_part); xn_part = fmaf(ra0.y, ra0.y, xn_part);
      xn_part = fmaf(ra0.z, ra0.z, xn_part); xn_part = fmaf(ra0.w, ra0.w, xn_part);
      xn_part = fmaf(ra1.x, ra1.x, xn_part); xn_part = fmaf(ra1.y, ra1.y, xn_part);
      xn_part = fmaf(ra1.z, ra1.z, xn_part); xn_part = fmaf(ra1.w, ra1.w, xn_part);
      Ah[aidx] = hv; Al[aidx] = lv;
      cvt8(rb[0], rb[1], hv, lv); Bh[bf00] = hv; Bl[bf00] = lv;
      cvt8(rb[2], rb[3], hv, lv); Bh[bf01] = hv; Bl[bf01] = lv;
      cvt8(rb[4], rb[5], hv, lv); Bh[bf10] = hv; Bl[bf10] = lv;
      cvt8(rb[6], rb[7], hv, lv); Bh[bf11] = hv; Bl[bf11] = lv;
    }
    __syncthreads();
    if (kt + 1 < NKT) {   // T14 prefetch under the MFMA phase
      const int ko = (kt + 1) * 32;
      ra0 = ld4(ap + ko);      ra1 = ld4(ap + ko + 4);
      rb[0] = ld4(bp0 + ko);      rb[1] = ld4(bp0 + ko + 4);
      rb[2] = ld4(bp0 + ko + 16); rb[3] = ld4(bp0 + ko + 20);
      rb[4] = ld4(bp1 + ko);      rb[5] = ld4(bp1 + ko + 4);
      rb[6] = ld4(bp1 + ko + 16); rb[7] = ld4(bp1 + ko + 20);
    }
    {
      half8 ah0 = Ah[(wm * 2 + 0) * 64 + lane];
      half8 al0 = Al[(wm * 2 + 0) * 64 + lane];
      half8 ah1 = Ah[(wm * 2 + 1) * 64 + lane];
      half8 al1 = Al[(wm * 2 + 1) * 64 + lane];
#pragma unroll
      for (int n = 0; n < 4; ++n) {
        const int nt = wn * 4 + n;
        half8 bh0 = Bh[(nt * 2 + 0) * 64 + lane], bl0 = Bl[(nt * 2 + 0) * 64 + lane];
        half8 bh1 = Bh[(nt * 2 + 1) * 64 + lane], bl1 = Bl[(nt * 2 + 1) * 64 + lane];
        // complete split: hi*hi + hi*lo + lo*hi + lo*lo
        acc[n] = __builtin_amdgcn_mfma_f32_32x32x16_f16(ah0, bh0, acc[n], 0, 0, 0);
        acc[n] = __builtin_amdgcn_mfma_f32_32x32x16_f16(ah0, bl0, acc[n], 0, 0, 0);
        acc[n] = __builtin_amdgcn_mfma_f32_32x32x16_f16(al0, bh0, acc[n], 0, 0, 0);
        acc[n] = __builtin_amdgcn_mfma_f32_32x32x16_f16(al0, bl0, acc[n], 0, 0, 0);
        acc[n] = __builtin_amdgcn_mfma_f32_32x32x16_f16(ah1, bh1, acc[n], 0, 0, 0);
        acc[n] = __builtin_amdgcn_mfma_f32_32x32x16_f16(ah1, bl1, acc[n], 0, 0, 0);
        acc[n] = __builtin_amdgcn_mfma_f32_32x32x16_f16(al1, bh1, acc[n], 0, 0, 0);
        acc[n] = __builtin_amdgcn_mfma_f32_32x32x16_f16(al1, bl1, acc[n], 0, 0, 0);
      }
    }
    __syncthreads();
  }

  xnp[amt * 32 + c31][akc * 2 + h] = xn_part;

  // ---- epilogue: approx top-2 per row via LDS scan, 2 batches of 32 rows ----
#pragma unroll 1
  for (int b = 0; b < 2; ++b) {
    __syncthreads();
    if (wm == b) {
#pragma unroll
      for (int n = 0; n < 4; ++n) {
        const int colbase = wn * 128 + n * 32 + c31;
#pragma unroll
        for (int rr = 0; rr < 16; ++rr) {
          const int row_b = (rr & 3) + ((rr >> 2) << 3) + (h << 2);
          const int p = colbase ^ ((row_b & 3) << 3);
          scanbuf[row_b * 256 + p] = fmaf(-2.f, acc[n][rr], en_s[colbase]);
        }
      }
    }
    __syncthreads();
    {
      const int srow = tid >> 3, chunk = tid & 7;
      float b1 = 1e30f, b2 = 1e30f; int i1 = 0, i2 = 0;
#pragma unroll
      for (int u = 0; u < 32; ++u) {
        const int col = chunk + u * 8;
        const float d = scanbuf[srow * 256 + (col ^ ((srow & 3) << 3))];
        if (d < b1) { b2 = b1; i2 = i1; b1 = d; i1 = col; }
        else if (d < b2) { b2 = d; i2 = col; }
      }
      red[srow][chunk] = make_float4(b1, __int_as_float(i1), b2, __int_as_float(i2));
    }
    __syncthreads();
    if (tid < 32) {
      float4 q = red[tid][0];
      float fb1 = q.x, fb2 = q.z;
      int fi1 = __float_as_int(q.y), fi2 = __float_as_int(q.w);
#pragma unroll
      for (int c = 1; c < 8; ++c) {
        q = red[tid][c];
        const float c1 = q.x, c2 = q.z;
        const int j1 = __float_as_int(q.y), j2 = __float_as_int(q.w);
        if (c1 < fb1 || (c1 == fb1 && j1 < fi1)) {
          if (fb1 < c2 || (fb1 == c2 && fi1 < j2)) { fb2 = fb1; fi2 = fi1; }
          else { fb2 = c2; fi2 = j2; }
          fb1 = c1; fi1 = j1;
        } else if (c1 < fb2 || (c1 == fb2 && j1 < fi2)) { fb2 = c1; fi2 = j1; }
      }
      rowres[b * 32 + tid] = make_float4(fb1, __int_as_float(fi1), fb2, __int_as_float(fi2));
    }
  }
  __syncthreads();

  // ---- finalize: write approx results; flag + compact near-ties ----
  if (tid < BM) {
    const int m = tid;
    const float4 qv = rowres[m];
    const float fb1 = qv.x, fb2 = qv.z;
    const int fi1 = __float_as_int(qv.y);
    const float xn = (xnp[m][0] + xnp[m][1]) + (xnp[m][2] + xnp[m][3]);
    idxs[m] = fi1;
    out_idx[m0 + m] = (float)fi1;
    dmin_lvl[m0 + m] = xn + fb1;
    xn_lvl[m0 + m] = xn;
    const bool flg = (fb2 - fb1 < RTAU);
    const unsigned long long mask = __ballot(flg);
    const int nf = __popcll(mask);
    int base = 0;
    if (tid == 0 && nf) base = atomicAdd(cnt, nf);
    base = __shfl(base, 0, 64);
    if (flg) {
      const int pos = __popcll(mask & ((1ull << tid) - 1ull));
      list[base + pos] = (int)(m0 + m);
    }
  }
  __syncthreads();

  // q = codebook[idx] (provisional for flagged rows; rescue overwrites)
  float* qb = out_q + m0 * (long)D_MODEL;
  for (int g = tid; g < BM * NSEG; g += 256) {
    const int m = g / NSEG;
    const int seg = g - m * NSEG;
    *(float4*)(qb + m * (long)D_MODEL + seg * 4) = ld4(cb + (long)idxs[m] * D_MODEL + seg * 4);
  }
}

// ---------------- exact rescue: full-row fp32 re-solve of flagged rows ----------------
__global__ __launch_bounds__(256) void vq_rescue(const float* __restrict__ x,
                                                 const float* __restrict__ cb,
                                                 const float* __restrict__ en_lvl,
                                                 const int* __restrict__ list,
                                                 const int* __restrict__ cnt,
                                                 float* __restrict__ out_idx,
                                                 float* __restrict__ out_q,
                                                 float* __restrict__ dmin_lvl,
                                                 const float* __restrict__ xn_lvl) {
  __shared__ float xs[8][D_MODEL];
  __shared__ int rows_s[8];
  __shared__ float xns_s[8];
  __shared__ float dall[8][256];
  __shared__ int best_s[8];
  const int tid = threadIdx.x;
  const int count = cnt[0];
  const int nch = (count + 7) >> 3;
  const float en_t = en_lvl[tid];
  const int w = tid >> 6, lane = tid & 63;
  const float* crow = cb + (long)tid * D_MODEL;

  for (int c = blockIdx.x; c < nch; c += gridDim.x) {
    const int base = c << 3;
    const int R = min(8, count - base);
    if (tid < 8) {
      const int j = min(tid, R - 1);
      const int r = list[base + j];
      rows_s[tid] = r;
      xns_s[tid] = xn_lvl[r];
    }
    __syncthreads();
#pragma unroll
    for (int r = 0; r < 8; ++r)
      if (tid < NSEG) *(float4*)&xs[r][tid * 4] = ld4(x + (long)rows_s[r] * D_MODEL + tid * 4);
    __syncthreads();

    float acc[8] = {0.f, 0.f, 0.f, 0.f, 0.f, 0.f, 0.f, 0.f};
    for (int seg = 0; seg < NSEG; ++seg) {     // exact ascending-k fp32 chain
      const float4 e = ld4(crow + seg * 4);
#pragma unroll
      for (int r = 0; r < 8; ++r) {
        const float4 xv = *(const float4*)&xs[r][seg * 4];
        acc[r] = fmaf(xv.x, e.x, acc[r]);
        acc[r] = fmaf(xv.y, e.y, acc[r]);
        acc[r] = fmaf(xv.z, e.z, acc[r]);
        acc[r] = fmaf(xv.w, e.w, acc[r]);
      }
    }
#pragma unroll
    for (int r = 0; r < 8; ++r)
      dall[r][tid] = fmaf(-2.f, acc[r], xns_s[r]) + en_t;   // round-1 d semantics
    __syncthreads();

#pragma unroll
    for (int rr = 0; rr < 2; ++rr) {
      const int r = w + rr * 4;
      if (r < R) {
        float best = dall[r][lane]; int bidx = lane;
#pragma unroll
        for (int u = 1; u < 4; ++u) {
          const int code = lane + u * 64;     // ascending per thread
          const float d = dall[r][code];
          if (d < best) { best = d; bidx = code; }
        }
        for (int mm = 1; mm < 64; mm <<= 1) {
          const float ov = __shfl_xor(best, mm, 64);
          const int oi = __shfl_xor(bidx, mm, 64);
          if (ov < best || (ov == best && oi < bidx)) { best = ov; bidx = oi; }
        }
        if (lane == 0) {
          const int row = rows_s[r];
          out_idx[row] = (float)bidx;
          dmin_lvl[row] = best;
          best_s[r] = bidx;
        }
      }
    }
    __syncthreads();
#pragma unroll
    for (int r = 0; r < 8; ++r)
      if (r < R && tid < NSEG)
        *(float4*)(out_q + (long)rows_s[r] * D_MODEL + tid * 4) =
            ld4(cb + (long)best_s[r] * D_MODEL + tid * 4);
    __syncthreads();
  }
}

// ---------------- deterministic loss reduce (after rescue) ----------------
__global__ __launch_bounds__(256) void loss_stage1(const float* __restrict__ dmin,
                                                   double* __restrict__ lp) {
  const int b = blockIdx.x;           // 576 blocks x 512 rows
  const int tid = threadIdx.x;
  const long r0 = (long)b * 512;
  __shared__ double sh[256];
  sh[tid] = (double)dmin[r0 + tid] + (double)dmin[r0 + 256 + tid];
  __syncthreads();
  for (int st = 128; st > 0; st >>= 1) {
    if (tid < st) sh[tid] += sh[tid + st];
    __syncthreads();
  }
  if (tid == 0) {
    double scale;
    if (b < 64)       scale = 0.05 / (32768.0 * 384.0);
    else if (b < 320) scale = 0.25 / (131072.0 * 384.0);
    else              scale = 0.60 / (131072.0 * 384.0);
    lp[b] = sh[0] * scale;
  }
}

__global__ __launch_bounds__(256) void loss_stage2(const double* __restrict__ lp,
                                                   float* __restrict__ out_loss) {
  const int tid = threadIdx.x;
  __shared__ double sh[256];
  sh[tid] = lp[tid] + lp[tid + 256] + ((tid < 64) ? lp[tid + 512] : 0.0);
  __syncthreads();
  for (int st = 128; st > 0; st >>= 1) {
    if (tid < st) sh[tid] += sh[tid + st];
    __syncthreads();
  }
  if (tid == 0) out_loss[0] = (float)sh[0];
}

extern "C" void kernel_launch(void* const* d_in, const int* in_sizes, int n_in,
                              void* d_out, int out_size, void* d_ws, size_t ws_size,
                              hipStream_t stream) {
  const float* l0 = (const float*)d_in[0];
  const float* l1 = (const float*)d_in[1];
  const float* l2 = (const float*)d_in[2];
  const float* c0 = (const float*)d_in[3];
  const float* c1 = (const float*)d_in[4];
  const float* c2 = (const float*)d_in[5];
  float* out = (float*)d_out;

  float* wsf = (float*)d_ws;
  int*   counts   = (int*)wsf;              // 4 ints
  float* en       = wsf + 4;                // 768
  float* dmin_all = wsf + 772;              // 294912
  float* xn_all   = wsf + 295684;           // 294912
  int*   list0    = (int*)(wsf + 590596);   // cap 32768
  int*   list1    = (int*)(wsf + 623364);   // cap 131072
  int*   list2    = (int*)(wsf + 754436);   // cap 131072
  double* lp      = (double*)(wsf + 885508);// 576 doubles

  vq_norms<<<768, 64, 0, stream>>>(c0, c1, c2, en, counts);

  vq_mfma<<<512, 256, 0, stream>>>(l0, c0, en, out + 0, out + 294913,
                                   dmin_all, xn_all, list0, counts + 0);
  vq_mfma<<<2048, 256, 0, stream>>>(l1, c1, en + 256, out + 32768, out + 12877825,
                                    dmin_all + 32768, xn_all + 32768, list1, counts + 1);
  vq_mfma<<<2048, 256, 0, stream>>>(l2, c2, en + 512, out + 163840, out + 63209473,
                                    dmin_all + 163840, xn_all + 163840, list2, counts + 2);

  vq_rescue<<<128, 256, 0, stream>>>(l0, c0, en, list0, counts + 0,
                                     out + 0, out + 294913, dmin_all, xn_all);
  vq_rescue<<<128, 256, 0, stream>>>(l1, c1, en + 256, list1, counts + 1,
                                     out + 32768, out + 12877825,
                                     dmin_all + 32768, xn_all + 32768);
  vq_rescue<<<128, 256, 0, stream>>>(l2, c2, en + 512, list2, counts + 2,
                                     out + 163840, out + 63209473,
                                     dmin_all + 163840, xn_all + 163840);

  loss_stage1<<<576, 256, 0, stream>>>(dmin_all, lp);
  loss_stage2<<<1, 256, 0, stream>>>(lp, out + 294912);
}

// Round 4
// 518.180 us; speedup vs baseline: 1.7298x; 1.1199x over previous
//
#include <hip/hip_runtime.h>

// SpatialHRVQTokenizer: 3-level VQ forward via f16-split MFMA GEMM + exact rescue.
// d2 = ||x||^2 - 2 x.e + ||e||^2 ; argmin (first-index ties) + q gather + loss.
// Output (flat fp32): idx0[0,32768) idx1[...,163840) idx2[...,294912)
//   loss[294912]  q0[294913..)  q1[12877825..)  q2[63209473..)
//
// ws layout (float units):
//   [0..4)            counts (int, per level)
//   [4..772)          en: code norms (768)
//   [772..295684)     dmin_all (294912)
//   [295684..590596)  xn_all   (294912)
//   [590596..623364)  list0 (cap 32768)
//   [623364..754436)  list1 (cap 131072)
//   [754436..885508)  list2 (cap 131072)
//   [885508..886660)  lp (576 doubles)
//   [886660..1034116) Bh_pre (36864 half8, frag-linear, 3 levels)
//   [1034116..1181572) Bl_pre            total ~4.73 MB

typedef _Float16 half8 __attribute__((ext_vector_type(8)));
typedef float f32x16 __attribute__((ext_vector_type(16)));

#define D_MODEL 384
#define NSEG 96
#define NKT 12
#define BM 64
#define RTAU 0.004f

__device__ __forceinline__ float4 ld4(const float* p) { return *(const float4*)p; }

__device__ __forceinline__ void cvt8(const float4& a, const float4& b, half8& hi, half8& lo) {
  const float v[8] = {a.x, a.y, a.z, a.w, b.x, b.y, b.z, b.w};
#pragma unroll
  for (int u = 0; u < 8; ++u) {
    _Float16 h = (_Float16)v[u];
    hi[u] = h;
    lo[u] = (_Float16)(v[u] - (float)h);
  }
}

__device__ __forceinline__ void gload_lds16(const void* g, void* l) {
  __builtin_amdgcn_global_load_lds(
      (const __attribute__((address_space(1))) unsigned int*)g,
      (__attribute__((address_space(3))) unsigned int*)l, 16, 0, 0);
}

// ---------------- code norms + counter zeroing ----------------
__global__ __launch_bounds__(64) void vq_norms(const float* __restrict__ c0,
                                               const float* __restrict__ c1,
                                               const float* __restrict__ c2,
                                               float* __restrict__ en,
                                               int* __restrict__ counts) {
  if (blockIdx.x == 0 && threadIdx.x < 4) counts[threadIdx.x] = 0;
  const int row = blockIdx.x;  // 0..767
  const float* cb = (row < 256) ? c0 : ((row < 512) ? c1 : c2);
  const int n = row & 255;
  const int lane = threadIdx.x;
  const float* r = cb + (size_t)n * D_MODEL;
  float s = 0.f;
  for (int c = lane; c < D_MODEL; c += 64) s = fmaf(r[c], r[c], s);
  for (int m = 1; m < 64; m <<= 1) s += __shfl_xor(s, m, 64);
  if (lane == 0) en[row] = s;
}

// ---------------- precompute split codebook, fragment-linear ----------------
// index t = ((lvl*12 + kt)*16 + f)*64 + lane ; f = nt*2+kc
// code = nt*32 + (lane&31) ; k0 = kt*32 + kc*16 + (lane>>5)*8
__global__ __launch_bounds__(256) void vq_split_cb(const float* __restrict__ c0,
                                                   const float* __restrict__ c1,
                                                   const float* __restrict__ c2,
                                                   half8* __restrict__ bh,
                                                   half8* __restrict__ bl) {
  const int t = blockIdx.x * 256 + threadIdx.x;    // 0..36863
  const int lvl = t / 12288;
  const int rem = t - lvl * 12288;
  const int kt = rem >> 10;
  const int f = (rem >> 6) & 15;
  const int lane = rem & 63;
  const int code = (f >> 1) * 32 + (lane & 31);
  const int k0 = kt * 32 + (f & 1) * 16 + (lane >> 5) * 8;
  const float* cb = (lvl == 0) ? c0 : ((lvl == 1) ? c1 : c2);
  const float4 a = ld4(cb + code * D_MODEL + k0);
  const float4 b = ld4(cb + code * D_MODEL + k0 + 4);
  half8 hv, lv;
  cvt8(a, b, hv, lv);
  bh[t] = hv;
  bl[t] = lv;
}

// ---------------- main fused VQ kernel (MFMA) ----------------
// 256 threads = 4 waves (2M x 2N). BM=64 rows x 256 codes, BK=32.
__global__ __launch_bounds__(256) void vq_mfma(const float* __restrict__ x,
                                               const float* __restrict__ cb,
                                               const float* __restrict__ en,
                                               const half8* __restrict__ bh_pre,
                                               const half8* __restrict__ bl_pre,
                                               float* __restrict__ out_idx,
                                               float* __restrict__ out_q,
                                               float* __restrict__ dmin_lvl,
                                               float* __restrict__ xn_lvl,
                                               int* __restrict__ list,
                                               int* __restrict__ cnt) {
  __shared__ __align__(16) unsigned char smem[40960];
  half8* Ah = (half8*)smem;                 //  4 KB
  half8* Al = (half8*)(smem + 4096);        //  4 KB
  half8* Bh = (half8*)(smem + 8192);        // 16 KB (frag-linear, gload_lds dest)
  half8* Bl = (half8*)(smem + 24576);       // 16 KB
  float* scanbuf = (float*)smem;            // [32][256] fp32, aliased post-K-loop
  __shared__ float en_s[256];
  __shared__ float4 red[32][8];
  __shared__ float4 rowres[BM];
  __shared__ float xnp[BM][4];
  __shared__ int   idxs[BM];

  const int tid = threadIdx.x;
  const int lane = tid & 63;
  const int w = tid >> 6, wm = w >> 1, wn = w & 1;
  const int c31 = lane & 31, h = lane >> 5;
  const long m0 = (long)blockIdx.x * BM;

  en_s[tid] = en[tid];

  const int amt = tid >> 7;            // A staging: m-tile
  const int akc = (tid >> 6) & 1;      //            k-chunk
  const float* ap = x + (m0 + amt * 32 + c31) * (long)D_MODEL + akc * 16 + h * 8;
  const int aidx = (amt * 2 + akc) * 64 + lane;

  float4 ra0 = ld4(ap + 0), ra1 = ld4(ap + 4);   // prologue A(0)

  f32x16 acc[4];
#pragma unroll
  for (int n = 0; n < 4; ++n)
#pragma unroll
    for (int i = 0; i < 16; ++i) acc[n][i] = 0.f;

  float xn_part = 0.f;

  for (int kt = 0; kt < NKT; ++kt) {
    // ---- stage phase: issue B direct-to-LDS first (hide L2 latency under A cvt)
#pragma unroll
    for (int r = 0; r < 4; ++r) {
      const int f = r * 4 + w;                       // wave-uniform frag id
      const size_t gi = (size_t)kt * 1024 + f * 64 + lane;
      gload_lds16(bh_pre + gi, (void*)(smem + 8192 + f * 1024));
      gload_lds16(bl_pre + gi, (void*)(smem + 24576 + f * 1024));
    }
    {
      half8 hv, lv;
      cvt8(ra0, ra1, hv, lv);
      xn_part = fmaf(ra0.x, ra0.x, xn_part); xn_part = fmaf(ra0.y, ra0.y, xn_part);
      xn_part = fmaf(ra0.z, ra0.z, xn_part); xn_part = fmaf(ra0.w, ra0.w, xn_part);
      xn_part = fmaf(ra1.x, ra1.x, xn_part); xn_part = fmaf(ra1.y, ra1.y, xn_part);
      xn_part = fmaf(ra1.z, ra1.z, xn_part); xn_part = fmaf(ra1.w, ra1.w, xn_part);
      Ah[aidx] = hv; Al[aidx] = lv;
    }
    __syncthreads();   // drains A ds_writes (lgkm) + B arrivals (vmcnt)

    // ---- compute phase
    if (kt + 1 < NKT) {   // T14: prefetch next A chunk under MFMAs
      const int ko = (kt + 1) * 32;
      ra0 = ld4(ap + ko); ra1 = ld4(ap + ko + 4);
    }
    {
      half8 ah0 = Ah[(wm * 2 + 0) * 64 + lane];
      half8 al0 = Al[(wm * 2 + 0) * 64 + lane];
      half8 ah1 = Ah[(wm * 2 + 1) * 64 + lane];
      half8 al1 = Al[(wm * 2 + 1) * 64 + lane];
#pragma unroll
      for (int n = 0; n < 4; ++n) {
        const int nt = wn * 4 + n;
        half8 bh0 = Bh[(nt * 2 + 0) * 64 + lane], bl0 = Bl[(nt * 2 + 0) * 64 + lane];
        half8 bh1 = Bh[(nt * 2 + 1) * 64 + lane], bl1 = Bl[(nt * 2 + 1) * 64 + lane];
        // 6-term split: hi*hi + hi*lo + lo*hi (lo*lo dropped; rescue covers)
        acc[n] = __builtin_amdgcn_mfma_f32_32x32x16_f16(ah0, bh0, acc[n], 0, 0, 0);
        acc[n] = __builtin_amdgcn_mfma_f32_32x32x16_f16(ah0, bl0, acc[n], 0, 0, 0);
        acc[n] = __builtin_amdgcn_mfma_f32_32x32x16_f16(al0, bh0, acc[n], 0, 0, 0);
        acc[n] = __builtin_amdgcn_mfma_f32_32x32x16_f16(ah1, bh1, acc[n], 0, 0, 0);
        acc[n] = __builtin_amdgcn_mfma_f32_32x32x16_f16(ah1, bl1, acc[n], 0, 0, 0);
        acc[n] = __builtin_amdgcn_mfma_f32_32x32x16_f16(al1, bh1, acc[n], 0, 0, 0);
      }
    }
    __syncthreads();   // LDS reused next kt
  }

  xnp[amt * 32 + c31][akc * 2 + h] = xn_part;

  // ---- epilogue: approx top-2 per row via LDS scan, 2 batches of 32 rows ----
#pragma unroll 1
  for (int b = 0; b < 2; ++b) {
    __syncthreads();
    if (wm == b) {
#pragma unroll
      for (int n = 0; n < 4; ++n) {
        const int colbase = wn * 128 + n * 32 + c31;
#pragma unroll
        for (int rr = 0; rr < 16; ++rr) {
          const int row_b = (rr & 3) + ((rr >> 2) << 3) + (h << 2);
          const int p = colbase ^ ((row_b & 3) << 3);
          scanbuf[row_b * 256 + p] = fmaf(-2.f, acc[n][rr], en_s[colbase]);
        }
      }
    }
    __syncthreads();
    {
      const int srow = tid >> 3, chunk = tid & 7;
      float b1 = 1e30f, b2 = 1e30f; int i1 = 0, i2 = 0;
#pragma unroll
      for (int u = 0; u < 32; ++u) {
        const int col = chunk + u * 8;
        const float d = scanbuf[srow * 256 + (col ^ ((srow & 3) << 3))];
        if (d < b1) { b2 = b1; i2 = i1; b1 = d; i1 = col; }
        else if (d < b2) { b2 = d; i2 = col; }
      }
      red[srow][chunk] = make_float4(b1, __int_as_float(i1), b2, __int_as_float(i2));
    }
    __syncthreads();
    if (tid < 32) {
      float4 q = red[tid][0];
      float fb1 = q.x, fb2 = q.z;
      int fi1 = __float_as_int(q.y), fi2 = __float_as_int(q.w);
#pragma unroll
      for (int c = 1; c < 8; ++c) {
        q = red[tid][c];
        const float c1 = q.x, c2 = q.z;
        const int j1 = __float_as_int(q.y), j2 = __float_as_int(q.w);
        if (c1 < fb1 || (c1 == fb1 && j1 < fi1)) {
          if (fb1 < c2 || (fb1 == c2 && fi1 < j2)) { fb2 = fb1; fi2 = fi1; }
          else { fb2 = c2; fi2 = j2; }
          fb1 = c1; fi1 = j1;
        } else if (c1 < fb2 || (c1 == fb2 && j1 < fi2)) { fb2 = c1; fi2 = j1; }
      }
      rowres[b * 32 + tid] = make_float4(fb1, __int_as_float(fi1), fb2, __int_as_float(fi2));
    }
  }
  __syncthreads();

  // ---- finalize: write approx results; flag + compact near-ties ----
  if (tid < BM) {
    const int m = tid;
    const float4 qv = rowres[m];
    const float fb1 = qv.x, fb2 = qv.z;
    const int fi1 = __float_as_int(qv.y);
    const float xn = (xnp[m][0] + xnp[m][1]) + (xnp[m][2] + xnp[m][3]);
    idxs[m] = fi1;
    out_idx[m0 + m] = (float)fi1;
    dmin_lvl[m0 + m] = xn + fb1;
    xn_lvl[m0 + m] = xn;
    const bool flg = (fb2 - fb1 < RTAU);
    const unsigned long long mask = __ballot(flg);
    const int nf = __popcll(mask);
    int base = 0;
    if (tid == 0 && nf) base = atomicAdd(cnt, nf);
    base = __shfl(base, 0, 64);
    if (flg) {
      const int pos = __popcll(mask & ((1ull << tid) - 1ull));
      list[base + pos] = (int)(m0 + m);
    }
  }
  __syncthreads();

  // q = codebook[idx] (provisional for flagged rows; rescue overwrites)
  float* qb = out_q + m0 * (long)D_MODEL;
  for (int g = tid; g < BM * NSEG; g += 256) {
    const int m = g / NSEG;
    const int seg = g - m * NSEG;
    *(float4*)(qb + m * (long)D_MODEL + seg * 4) = ld4(cb + (long)idxs[m] * D_MODEL + seg * 4);
  }
}

// ---------------- exact rescue: full-row fp32 re-solve of flagged rows ----------------
__global__ __launch_bounds__(256) void vq_rescue(const float* __restrict__ x,
                                                 const float* __restrict__ cb,
                                                 const float* __restrict__ en_lvl,
                                                 const int* __restrict__ list,
                                                 const int* __restrict__ cnt,
                                                 float* __restrict__ out_idx,
                                                 float* __restrict__ out_q,
                                                 float* __restrict__ dmin_lvl,
                                                 const float* __restrict__ xn_lvl) {
  __shared__ float xs[8][D_MODEL];
  __shared__ int rows_s[8];
  __shared__ float xns_s[8];
  __shared__ float dall[8][256];
  __shared__ int best_s[8];
  const int tid = threadIdx.x;
  const int count = cnt[0];
  const int nch = (count + 7) >> 3;
  const float en_t = en_lvl[tid];
  const int w = tid >> 6, lane = tid & 63;
  const float* crow = cb + (long)tid * D_MODEL;

  for (int c = blockIdx.x; c < nch; c += gridDim.x) {
    const int base = c << 3;
    const int R = min(8, count - base);
    if (tid < 8) {
      const int j = min(tid, R - 1);
      const int r = list[base + j];
      rows_s[tid] = r;
      xns_s[tid] = xn_lvl[r];
    }
    __syncthreads();
#pragma unroll
    for (int r = 0; r < 8; ++r)
      if (tid < NSEG) *(float4*)&xs[r][tid * 4] = ld4(x + (long)rows_s[r] * D_MODEL + tid * 4);
    __syncthreads();

    float acc[8] = {0.f, 0.f, 0.f, 0.f, 0.f, 0.f, 0.f, 0.f};
    for (int seg = 0; seg < NSEG; ++seg) {     // exact ascending-k fp32 chain
      const float4 e = ld4(crow + seg * 4);
#pragma unroll
      for (int r = 0; r < 8; ++r) {
        const float4 xv = *(const float4*)&xs[r][seg * 4];
        acc[r] = fmaf(xv.x, e.x, acc[r]);
        acc[r] = fmaf(xv.y, e.y, acc[r]);
        acc[r] = fmaf(xv.z, e.z, acc[r]);
        acc[r] = fmaf(xv.w, e.w, acc[r]);
      }
    }
#pragma unroll
    for (int r = 0; r < 8; ++r)
      dall[r][tid] = fmaf(-2.f, acc[r], xns_s[r]) + en_t;
    __syncthreads();

#pragma unroll
    for (int rr = 0; rr < 2; ++rr) {
      const int r = w + rr * 4;
      if (r < R) {
        float best = dall[r][lane]; int bidx = lane;
#pragma unroll
        for (int u = 1; u < 4; ++u) {
          const int code = lane + u * 64;
          const float d = dall[r][code];
          if (d < best) { best = d; bidx = code; }
        }
        for (int mm = 1; mm < 64; mm <<= 1) {
          const float ov = __shfl_xor(best, mm, 64);
          const int oi = __shfl_xor(bidx, mm, 64);
          if (ov < best || (ov == best && oi < bidx)) { best = ov; bidx = oi; }
        }
        if (lane == 0) {
          const int row = rows_s[r];
          out_idx[row] = (float)bidx;
          dmin_lvl[row] = best;
          best_s[r] = bidx;
        }
      }
    }
    __syncthreads();
#pragma unroll
    for (int r = 0; r < 8; ++r)
      if (r < R && tid < NSEG)
        *(float4*)(out_q + (long)rows_s[r] * D_MODEL + tid * 4) =
            ld4(cb + (long)best_s[r] * D_MODEL + tid * 4);
    __syncthreads();
  }
}

// ---------------- deterministic loss reduce (after rescue) ----------------
__global__ __launch_bounds__(256) void loss_stage1(const float* __restrict__ dmin,
                                                   double* __restrict__ lp) {
  const int b = blockIdx.x;           // 576 blocks x 512 rows
  const int tid = threadIdx.x;
  const long r0 = (long)b * 512;
  __shared__ double sh[256];
  sh[tid] = (double)dmin[r0 + tid] + (double)dmin[r0 + 256 + tid];
  __syncthreads();
  for (int st = 128; st > 0; st >>= 1) {
    if (tid < st) sh[tid] += sh[tid + st];
    __syncthreads();
  }
  if (tid == 0) {
    double scale;
    if (b < 64)       scale = 0.05 / (32768.0 * 384.0);
    else if (b < 320) scale = 0.25 / (131072.0 * 384.0);
    else              scale = 0.60 / (131072.0 * 384.0);
    lp[b] = sh[0] * scale;
  }
}

__global__ __launch_bounds__(256) void loss_stage2(const double* __restrict__ lp,
                                                   float* __restrict__ out_loss) {
  const int tid = threadIdx.x;
  __shared__ double sh[256];
  sh[tid] = lp[tid] + lp[tid + 256] + ((tid < 64) ? lp[tid + 512] : 0.0);
  __syncthreads();
  for (int st = 128; st > 0; st >>= 1) {
    if (tid < st) sh[tid] += sh[tid + st];
    __syncthreads();
  }
  if (tid == 0) out_loss[0] = (float)sh[0];
}

extern "C" void kernel_launch(void* const* d_in, const int* in_sizes, int n_in,
                              void* d_out, int out_size, void* d_ws, size_t ws_size,
                              hipStream_t stream) {
  const float* l0 = (const float*)d_in[0];
  const float* l1 = (const float*)d_in[1];
  const float* l2 = (const float*)d_in[2];
  const float* c0 = (const float*)d_in[3];
  const float* c1 = (const float*)d_in[4];
  const float* c2 = (const float*)d_in[5];
  float* out = (float*)d_out;

  float* wsf = (float*)d_ws;
  int*   counts   = (int*)wsf;               // 4 ints
  float* en       = wsf + 4;                 // 768
  float* dmin_all = wsf + 772;               // 294912
  float* xn_all   = wsf + 295684;            // 294912
  int*   list0    = (int*)(wsf + 590596);    // cap 32768
  int*   list1    = (int*)(wsf + 623364);    // cap 131072
  int*   list2    = (int*)(wsf + 754436);    // cap 131072
  double* lp      = (double*)(wsf + 885508); // 576 doubles
  half8* bh_pre   = (half8*)(wsf + 886660);  // 36864 half8 (16B-aligned)
  half8* bl_pre   = (half8*)(wsf + 1034116); // 36864 half8

  vq_norms<<<768, 64, 0, stream>>>(c0, c1, c2, en, counts);
  vq_split_cb<<<144, 256, 0, stream>>>(c0, c1, c2, bh_pre, bl_pre);

  vq_mfma<<<512, 256, 0, stream>>>(l0, c0, en, bh_pre, bl_pre,
                                   out + 0, out + 294913,
                                   dmin_all, xn_all, list0, counts + 0);
  vq_mfma<<<2048, 256, 0, stream>>>(l1, c1, en + 256, bh_pre + 12288, bl_pre + 12288,
                                    out + 32768, out + 12877825,
                                    dmin_all + 32768, xn_all + 32768, list1, counts + 1);
  vq_mfma<<<2048, 256, 0, stream>>>(l2, c2, en + 512, bh_pre + 24576, bl_pre + 24576,
                                    out + 163840, out + 63209473,
                                    dmin_all + 163840, xn_all + 163840, list2, counts + 2);

  vq_rescue<<<128, 256, 0, stream>>>(l0, c0, en, list0, counts + 0,
                                     out + 0, out + 294913, dmin_all, xn_all);
  vq_rescue<<<128, 256, 0, stream>>>(l1, c1, en + 256, list1, counts + 1,
                                     out + 32768, out + 12877825,
                                     dmin_all + 32768, xn_all + 32768);
  vq_rescue<<<128, 256, 0, stream>>>(l2, c2, en + 512, list2, counts + 2,
                                     out + 163840, out + 63209473,
                                     dmin_all + 163840, xn_all + 163840);

  loss_stage1<<<576, 256, 0, stream>>>(dmin_all, lp);
  loss_stage2<<<1, 256, 0, stream>>>(lp, out + 294912);
}

// Round 5
// 428.488 us; speedup vs baseline: 2.0919x; 1.2093x over previous
//
#include <hip/hip_runtime.h>

// SpatialHRVQTokenizer: 3-level VQ forward via f16-split MFMA GEMM + exact rescue.
// d2 = ||x||^2 - 2 x.e + ||e||^2 ; argmin (first-index ties) + q gather + loss.
// Output (flat fp32): idx0[0,32768) idx1[...,163840) idx2[...,294912)
//   loss[294912]  q0[294913..)  q1[12877825..)  q2[63209473..)
//
// ws layout (float units):
//   [0..4)            counts (int, per level)
//   [4..772)          en: code norms (768)
//   [772..295684)     dmin_all (294912)
//   [295684..590596)  xn_all   (294912)
//   [590596..623364)  list0 (cap 32768)
//   [623364..754436)  list1 (cap 131072)
//   [754436..885508)  list2 (cap 131072)
//   [885508..886660)  lp (576 doubles)
//   [886660..1034116) Bh_pre (36864 half8, frag-linear, 3 levels)
//   [1034116..1181572) Bl_pre

typedef _Float16 half8 __attribute__((ext_vector_type(8)));
typedef float f32x16 __attribute__((ext_vector_type(16)));

#define D_MODEL 384
#define NSEG 96
#define NKT 12
#define BM 64
#define RTAU 0.004f

__device__ __forceinline__ float4 ld4(const float* p) { return *(const float4*)p; }

__device__ __forceinline__ void cvt8(const float4& a, const float4& b, half8& hi, half8& lo) {
  const float v[8] = {a.x, a.y, a.z, a.w, b.x, b.y, b.z, b.w};
#pragma unroll
  for (int u = 0; u < 8; ++u) {
    _Float16 h = (_Float16)v[u];
    hi[u] = h;
    lo[u] = (_Float16)(v[u] - (float)h);
  }
}

__device__ __forceinline__ void gload_lds16(const void* g, void* l) {
  __builtin_amdgcn_global_load_lds(
      (const __attribute__((address_space(1))) unsigned int*)g,
      (__attribute__((address_space(3))) unsigned int*)l, 16, 0, 0);
}

// ---------------- code norms + counter zeroing ----------------
__global__ __launch_bounds__(64) void vq_norms(const float* __restrict__ c0,
                                               const float* __restrict__ c1,
                                               const float* __restrict__ c2,
                                               float* __restrict__ en,
                                               int* __restrict__ counts) {
  if (blockIdx.x == 0 && threadIdx.x < 4) counts[threadIdx.x] = 0;
  const int row = blockIdx.x;  // 0..767
  const float* cb = (row < 256) ? c0 : ((row < 512) ? c1 : c2);
  const int n = row & 255;
  const int lane = threadIdx.x;
  const float* r = cb + (size_t)n * D_MODEL;
  float s = 0.f;
  for (int c = lane; c < D_MODEL; c += 64) s = fmaf(r[c], r[c], s);
  for (int m = 1; m < 64; m <<= 1) s += __shfl_xor(s, m, 64);
  if (lane == 0) en[row] = s;
}

// ---------------- precompute split codebook, fragment-linear ----------------
__global__ __launch_bounds__(256) void vq_split_cb(const float* __restrict__ c0,
                                                   const float* __restrict__ c1,
                                                   const float* __restrict__ c2,
                                                   half8* __restrict__ bh,
                                                   half8* __restrict__ bl) {
  const int t = blockIdx.x * 256 + threadIdx.x;    // 0..36863
  const int lvl = t / 12288;
  const int rem = t - lvl * 12288;
  const int kt = rem >> 10;
  const int f = (rem >> 6) & 15;
  const int lane = rem & 63;
  const int code = (f >> 1) * 32 + (lane & 31);
  const int k0 = kt * 32 + (f & 1) * 16 + (lane >> 5) * 8;
  const float* cb = (lvl == 0) ? c0 : ((lvl == 1) ? c1 : c2);
  const float4 a = ld4(cb + code * D_MODEL + k0);
  const float4 b = ld4(cb + code * D_MODEL + k0 + 4);
  half8 hv, lv;
  cvt8(a, b, hv, lv);
  bh[t] = hv;
  bl[t] = lv;
}

// ---------------- fused main VQ kernel, all 3 levels ----------------
// 4608 blocks (XCD-swizzled), 256 threads = 4 waves (2M x 2N).
// BM=64 rows x 256 codes, BK=32. LDS exactly 40960 B -> 4 blocks/CU.
__global__ __launch_bounds__(256) void vq_mfma_all(
    const float* __restrict__ l0, const float* __restrict__ l1,
    const float* __restrict__ l2, const float* __restrict__ c0,
    const float* __restrict__ c1, const float* __restrict__ c2,
    const float* __restrict__ en_all,
    const half8* __restrict__ bh_pre, const half8* __restrict__ bl_pre,
    float* __restrict__ out, float* __restrict__ dmin_all,
    float* __restrict__ xn_all,
    int* __restrict__ list0, int* __restrict__ list1, int* __restrict__ list2,
    int* __restrict__ counts) {
  __shared__ __align__(16) unsigned char smem[40960];
  // K-loop layout:
  half8* Ah = (half8*)smem;                 //     0.. 4096
  half8* Al = (half8*)(smem + 4096);        //  4096.. 8192
  //   Bh: 8192..24576, Bl: 24576..40960 (gload_lds dest, frag-linear)
  // post-K-loop aliases (all first touched after final K-loop barrier):
  float*  scanbuf = (float*)smem;           //     0..32768  [32][256]
  float4* red     = (float4*)(smem + 32768);// 32768..36864  [32][8]
  float*  en_s    = (float*)(smem + 36864); // 36864..37888  [256]
  float4* rowres  = (float4*)(smem + 37888);// 37888..38912  [64]
  float*  xnp     = (float*)(smem + 38912); // 38912..39936  [64][4]
  int*    idxs    = (int*)(smem + 39936);   // 39936..40192  [64]

  // ---- level decode with bijective XCD swizzle (4608 % 8 == 0) ----
  const int swz = (blockIdx.x & 7) * 576 + (blockIdx.x >> 3);
  int lvl, blk;
  if (swz < 512)       { lvl = 0; blk = swz; }
  else if (swz < 2560) { lvl = 1; blk = swz - 512; }
  else                 { lvl = 2; blk = swz - 2560; }
  const float* x  = (lvl == 0) ? l0 : ((lvl == 1) ? l1 : l2);
  const float* cb = (lvl == 0) ? c0 : ((lvl == 1) ? c1 : c2);
  const float* en = en_all + lvl * 256;
  const half8* bh = bh_pre + lvl * 12288;
  const half8* bl = bl_pre + lvl * 12288;
  const long ioff = (lvl == 0) ? 0 : ((lvl == 1) ? 32768 : 163840);
  float* out_idx = out + ioff;
  float* out_q   = out + ((lvl == 0) ? 294913L : ((lvl == 1) ? 12877825L : 63209473L));
  float* dmin_lvl = dmin_all + ioff;
  float* xn_lvl   = xn_all + ioff;
  int* list = (lvl == 0) ? list0 : ((lvl == 1) ? list1 : list2);
  int* cnt  = counts + lvl;

  const int tid = threadIdx.x;
  const int lane = tid & 63;
  const int w = tid >> 6, wm = w >> 1, wn = w & 1;
  const int c31 = lane & 31, h = lane >> 5;
  const long m0 = (long)blk * BM;

  const int amt = tid >> 7;            // A staging: m-tile
  const int akc = (tid >> 6) & 1;      //            k-chunk
  const float* ap = x + (m0 + amt * 32 + c31) * (long)D_MODEL + akc * 16 + h * 8;
  const int aidx = (amt * 2 + akc) * 64 + lane;

  float4 ra0 = ld4(ap + 0), ra1 = ld4(ap + 4);   // prologue A(0)

  f32x16 acc[4];
#pragma unroll
  for (int n = 0; n < 4; ++n)
#pragma unroll
    for (int i = 0; i < 16; ++i) acc[n][i] = 0.f;

  float xn_part = 0.f;

  for (int kt = 0; kt < NKT; ++kt) {
    // stage: issue B direct-to-LDS first (L2 latency hides under A cvt)
#pragma unroll
    for (int r = 0; r < 4; ++r) {
      const int f = r * 4 + w;                       // wave-uniform frag id
      const size_t gi = (size_t)kt * 1024 + f * 64 + lane;
      gload_lds16(bh + gi, (void*)(smem + 8192 + f * 1024));
      gload_lds16(bl + gi, (void*)(smem + 24576 + f * 1024));
    }
    {
      half8 hv, lv;
      cvt8(ra0, ra1, hv, lv);
      xn_part = fmaf(ra0.x, ra0.x, xn_part); xn_part = fmaf(ra0.y, ra0.y, xn_part);
      xn_part = fmaf(ra0.z, ra0.z, xn_part); xn_part = fmaf(ra0.w, ra0.w, xn_part);
      xn_part = fmaf(ra1.x, ra1.x, xn_part); xn_part = fmaf(ra1.y, ra1.y, xn_part);
      xn_part = fmaf(ra1.z, ra1.z, xn_part); xn_part = fmaf(ra1.w, ra1.w, xn_part);
      Ah[aidx] = hv; Al[aidx] = lv;
    }
    __syncthreads();   // drains A ds_writes + B gload arrivals

    if (kt + 1 < NKT) {   // T14: prefetch next A chunk under MFMAs
      const int ko = (kt + 1) * 32;
      ra0 = ld4(ap + ko); ra1 = ld4(ap + ko + 4);
    }
    {
      half8* Bh = (half8*)(smem + 8192);
      half8* Bl = (half8*)(smem + 24576);
      half8 ah0 = Ah[(wm * 2 + 0) * 64 + lane];
      half8 al0 = Al[(wm * 2 + 0) * 64 + lane];
      half8 ah1 = Ah[(wm * 2 + 1) * 64 + lane];
      half8 al1 = Al[(wm * 2 + 1) * 64 + lane];
#pragma unroll
      for (int n = 0; n < 4; ++n) {
        const int nt = wn * 4 + n;
        half8 bh0 = Bh[(nt * 2 + 0) * 64 + lane], bl0 = Bl[(nt * 2 + 0) * 64 + lane];
        half8 bh1 = Bh[(nt * 2 + 1) * 64 + lane], bl1 = Bl[(nt * 2 + 1) * 64 + lane];
        // 6-term split: hi*hi + hi*lo + lo*hi (lo*lo dropped; rescue covers)
        acc[n] = __builtin_amdgcn_mfma_f32_32x32x16_f16(ah0, bh0, acc[n], 0, 0, 0);
        acc[n] = __builtin_amdgcn_mfma_f32_32x32x16_f16(ah0, bl0, acc[n], 0, 0, 0);
        acc[n] = __builtin_amdgcn_mfma_f32_32x32x16_f16(al0, bh0, acc[n], 0, 0, 0);
        acc[n] = __builtin_amdgcn_mfma_f32_32x32x16_f16(ah1, bh1, acc[n], 0, 0, 0);
        acc[n] = __builtin_amdgcn_mfma_f32_32x32x16_f16(ah1, bl1, acc[n], 0, 0, 0);
        acc[n] = __builtin_amdgcn_mfma_f32_32x32x16_f16(al1, bh1, acc[n], 0, 0, 0);
      }
    }
    __syncthreads();
  }

  // post-loop: B/A LDS dead; populate aliased epilogue structures
  xnp[(amt * 32 + c31) * 4 + (akc * 2 + h)] = xn_part;
  en_s[tid] = en[tid];

  // ---- epilogue: approx top-2 per row via LDS scan, 2 batches of 32 rows ----
#pragma unroll 1
  for (int b = 0; b < 2; ++b) {
    __syncthreads();
    if (wm == b) {
#pragma unroll
      for (int n = 0; n < 4; ++n) {
        const int colbase = wn * 128 + n * 32 + c31;
#pragma unroll
        for (int rr = 0; rr < 16; ++rr) {
          const int row_b = (rr & 3) + ((rr >> 2) << 3) + (h << 2);
          const int p = colbase ^ ((row_b & 3) << 3);
          scanbuf[row_b * 256 + p] = fmaf(-2.f, acc[n][rr], en_s[colbase]);
        }
      }
    }
    __syncthreads();
    {
      const int srow = tid >> 3, chunk = tid & 7;
      float b1 = 1e30f, b2 = 1e30f; int i1 = 0, i2 = 0;
#pragma unroll
      for (int u = 0; u < 32; ++u) {
        const int col = chunk + u * 8;
        const float d = scanbuf[srow * 256 + (col ^ ((srow & 3) << 3))];
        if (d < b1) { b2 = b1; i2 = i1; b1 = d; i1 = col; }
        else if (d < b2) { b2 = d; i2 = col; }
      }
      red[srow * 8 + chunk] = make_float4(b1, __int_as_float(i1), b2, __int_as_float(i2));
    }
    __syncthreads();
    if (tid < 32) {
      float4 q = red[tid * 8 + 0];
      float fb1 = q.x, fb2 = q.z;
      int fi1 = __float_as_int(q.y), fi2 = __float_as_int(q.w);
#pragma unroll
      for (int c = 1; c < 8; ++c) {
        q = red[tid * 8 + c];
        const float c1 = q.x, c2 = q.z;
        const int j1 = __float_as_int(q.y), j2 = __float_as_int(q.w);
        if (c1 < fb1 || (c1 == fb1 && j1 < fi1)) {
          if (fb1 < c2 || (fb1 == c2 && fi1 < j2)) { fb2 = fb1; fi2 = fi1; }
          else { fb2 = c2; fi2 = j2; }
          fb1 = c1; fi1 = j1;
        } else if (c1 < fb2 || (c1 == fb2 && j1 < fi2)) { fb2 = c1; fi2 = j1; }
      }
      rowres[b * 32 + tid] = make_float4(fb1, __int_as_float(fi1), fb2, __int_as_float(fi2));
    }
  }
  __syncthreads();

  // ---- finalize: write approx results; flag + compact near-ties ----
  if (tid < BM) {
    const int m = tid;
    const float4 qv = rowres[m];
    const float fb1 = qv.x, fb2 = qv.z;
    const int fi1 = __float_as_int(qv.y);
    const float xn = (xnp[m * 4 + 0] + xnp[m * 4 + 1]) + (xnp[m * 4 + 2] + xnp[m * 4 + 3]);
    idxs[m] = fi1;
    out_idx[m0 + m] = (float)fi1;
    dmin_lvl[m0 + m] = xn + fb1;
    xn_lvl[m0 + m] = xn;
    const bool flg = (fb2 - fb1 < RTAU);
    const unsigned long long mask = __ballot(flg);
    const int nf = __popcll(mask);
    int base = 0;
    if (tid == 0 && nf) base = atomicAdd(cnt, nf);
    base = __shfl(base, 0, 64);
    if (flg) {
      const int pos = __popcll(mask & ((1ull << tid) - 1ull));
      list[base + pos] = (int)(m0 + m);
    }
  }
  __syncthreads();

  // q = codebook[idx] (provisional for flagged rows; rescue overwrites)
  float* qb = out_q + m0 * (long)D_MODEL;
  for (int g = tid; g < BM * NSEG; g += 256) {
    const int m = g / NSEG;
    const int seg = g - m * NSEG;
    *(float4*)(qb + m * (long)D_MODEL + seg * 4) = ld4(cb + (long)idxs[m] * D_MODEL + seg * 4);
  }
}

// ---------------- fused exact rescue, all 3 levels ----------------
__global__ __launch_bounds__(256) void vq_rescue_all(
    const float* __restrict__ l0, const float* __restrict__ l1,
    const float* __restrict__ l2, const float* __restrict__ c0,
    const float* __restrict__ c1, const float* __restrict__ c2,
    const float* __restrict__ en_all,
    const int* __restrict__ list0, const int* __restrict__ list1,
    const int* __restrict__ list2, const int* __restrict__ counts,
    float* __restrict__ out, float* __restrict__ dmin_all,
    const float* __restrict__ xn_all) {
  __shared__ float xs[8][D_MODEL];
  __shared__ int rows_s[8];
  __shared__ float xns_s[8];
  __shared__ float dall[8][256];
  __shared__ int best_s[8];

  const int lvl = blockIdx.x >> 7;          // 128 blocks per level
  const int sb  = blockIdx.x & 127;
  const float* x  = (lvl == 0) ? l0 : ((lvl == 1) ? l1 : l2);
  const float* cb = (lvl == 0) ? c0 : ((lvl == 1) ? c1 : c2);
  const float* en_lvl = en_all + lvl * 256;
  const int* list = (lvl == 0) ? list0 : ((lvl == 1) ? list1 : list2);
  const long ioff = (lvl == 0) ? 0 : ((lvl == 1) ? 32768 : 163840);
  float* out_idx = out + ioff;
  float* out_q   = out + ((lvl == 0) ? 294913L : ((lvl == 1) ? 12877825L : 63209473L));
  float* dmin_lvl = dmin_all + ioff;
  const float* xn_lvl = xn_all + ioff;

  const int tid = threadIdx.x;
  const int count = counts[lvl];
  const int nch = (count + 7) >> 3;
  const float en_t = en_lvl[tid];
  const int w = tid >> 6, lane = tid & 63;
  const float* crow = cb + (long)tid * D_MODEL;

  for (int c = sb; c < nch; c += 128) {
    const int base = c << 3;
    const int R = min(8, count - base);
    if (tid < 8) {
      const int j = min(tid, R - 1);
      const int r = list[base + j];
      rows_s[tid] = r;
      xns_s[tid] = xn_lvl[r];
    }
    __syncthreads();
#pragma unroll
    for (int r = 0; r < 8; ++r)
      if (tid < NSEG) *(float4*)&xs[r][tid * 4] = ld4(x + (long)rows_s[r] * D_MODEL + tid * 4);
    __syncthreads();

    float acc[8] = {0.f, 0.f, 0.f, 0.f, 0.f, 0.f, 0.f, 0.f};
    for (int seg = 0; seg < NSEG; ++seg) {     // exact ascending-k fp32 chain
      const float4 e = ld4(crow + seg * 4);
#pragma unroll
      for (int r = 0; r < 8; ++r) {
        const float4 xv = *(const float4*)&xs[r][seg * 4];
        acc[r] = fmaf(xv.x, e.x, acc[r]);
        acc[r] = fmaf(xv.y, e.y, acc[r]);
        acc[r] = fmaf(xv.z, e.z, acc[r]);
        acc[r] = fmaf(xv.w, e.w, acc[r]);
      }
    }
#pragma unroll
    for (int r = 0; r < 8; ++r)
      dall[r][tid] = fmaf(-2.f, acc[r], xns_s[r]) + en_t;
    __syncthreads();

#pragma unroll
    for (int rr = 0; rr < 2; ++rr) {
      const int r = w + rr * 4;
      if (r < R) {
        float best = dall[r][lane]; int bidx = lane;
#pragma unroll
        for (int u = 1; u < 4; ++u) {
          const int code = lane + u * 64;
          const float d = dall[r][code];
          if (d < best) { best = d; bidx = code; }
        }
        for (int mm = 1; mm < 64; mm <<= 1) {
          const float ov = __shfl_xor(best, mm, 64);
          const int oi = __shfl_xor(bidx, mm, 64);
          if (ov < best || (ov == best && oi < bidx)) { best = ov; bidx = oi; }
        }
        if (lane == 0) {
          const int row = rows_s[r];
          out_idx[row] = (float)bidx;
          dmin_lvl[row] = best;
          best_s[r] = bidx;
        }
      }
    }
    __syncthreads();
#pragma unroll
    for (int r = 0; r < 8; ++r)
      if (r < R && tid < NSEG)
        *(float4*)(out_q + (long)rows_s[r] * D_MODEL + tid * 4) =
            ld4(cb + (long)best_s[r] * D_MODEL + tid * 4);
    __syncthreads();
  }
}

// ---------------- deterministic loss reduce (after rescue) ----------------
__global__ __launch_bounds__(256) void loss_stage1(const float* __restrict__ dmin,
                                                   double* __restrict__ lp) {
  const int b = blockIdx.x;           // 576 blocks x 512 rows
  const int tid = threadIdx.x;
  const long r0 = (long)b * 512;
  __shared__ double sh[256];
  sh[tid] = (double)dmin[r0 + tid] + (double)dmin[r0 + 256 + tid];
  __syncthreads();
  for (int st = 128; st > 0; st >>= 1) {
    if (tid < st) sh[tid] += sh[tid + st];
    __syncthreads();
  }
  if (tid == 0) {
    double scale;
    if (b < 64)       scale = 0.05 / (32768.0 * 384.0);
    else if (b < 320) scale = 0.25 / (131072.0 * 384.0);
    else              scale = 0.60 / (131072.0 * 384.0);
    lp[b] = sh[0] * scale;
  }
}

__global__ __launch_bounds__(256) void loss_stage2(const double* __restrict__ lp,
                                                   float* __restrict__ out_loss) {
  const int tid = threadIdx.x;
  __shared__ double sh[256];
  sh[tid] = lp[tid] + lp[tid + 256] + ((tid < 64) ? lp[tid + 512] : 0.0);
  __syncthreads();
  for (int st = 128; st > 0; st >>= 1) {
    if (tid < st) sh[tid] += sh[tid + st];
    __syncthreads();
  }
  if (tid == 0) out_loss[0] = (float)sh[0];
}

extern "C" void kernel_launch(void* const* d_in, const int* in_sizes, int n_in,
                              void* d_out, int out_size, void* d_ws, size_t ws_size,
                              hipStream_t stream) {
  const float* l0 = (const float*)d_in[0];
  const float* l1 = (const float*)d_in[1];
  const float* l2 = (const float*)d_in[2];
  const float* c0 = (const float*)d_in[3];
  const float* c1 = (const float*)d_in[4];
  const float* c2 = (const float*)d_in[5];
  float* out = (float*)d_out;

  float* wsf = (float*)d_ws;
  int*   counts   = (int*)wsf;               // 4 ints
  float* en       = wsf + 4;                 // 768
  float* dmin_all = wsf + 772;               // 294912
  float* xn_all   = wsf + 295684;            // 294912
  int*   list0    = (int*)(wsf + 590596);    // cap 32768
  int*   list1    = (int*)(wsf + 623364);    // cap 131072
  int*   list2    = (int*)(wsf + 754436);    // cap 131072
  double* lp      = (double*)(wsf + 885508); // 576 doubles
  half8* bh_pre   = (half8*)(wsf + 886660);  // 36864 half8 (16B-aligned)
  half8* bl_pre   = (half8*)(wsf + 1034116); // 36864 half8

  vq_norms<<<768, 64, 0, stream>>>(c0, c1, c2, en, counts);
  vq_split_cb<<<144, 256, 0, stream>>>(c0, c1, c2, bh_pre, bl_pre);

  vq_mfma_all<<<4608, 256, 0, stream>>>(l0, l1, l2, c0, c1, c2, en,
                                        bh_pre, bl_pre, out,
                                        dmin_all, xn_all,
                                        list0, list1, list2, counts);

  vq_rescue_all<<<384, 256, 0, stream>>>(l0, l1, l2, c0, c1, c2, en,
                                         list0, list1, list2, counts,
                                         out, dmin_all, xn_all);

  loss_stage1<<<576, 256, 0, stream>>>(dmin_all, lp);
  loss_stage2<<<1, 256, 0, stream>>>(lp, out + 294912);
}

// Round 7
// 397.962 us; speedup vs baseline: 2.2523x; 1.0767x over previous
//
#include <hip/hip_runtime.h>

// SpatialHRVQTokenizer: 3-level VQ forward via f16-split MFMA GEMM + exact rescue.
// d2 = ||x||^2 - 2 x.e + ||e||^2 ; argmin (first-index ties) + q gather + loss.
// Output (flat fp32): idx0[0,32768) idx1[...,163840) idx2[...,294912)
//   loss[294912]  q0[294913..)  q1[12877825..)  q2[63209473..)

typedef _Float16 half8 __attribute__((ext_vector_type(8)));
typedef float f32x16 __attribute__((ext_vector_type(16)));

#define D_MODEL 384
#define NSEG 96
#define NKT 12
#define BM 64
#define RTAU 0.004f

__device__ __forceinline__ float4 ld4(const float* p) { return *(const float4*)p; }

__device__ __forceinline__ void cvt8(const float4& a, const float4& b, half8& hi, half8& lo) {
  const float v[8] = {a.x, a.y, a.z, a.w, b.x, b.y, b.z, b.w};
#pragma unroll
  for (int u = 0; u < 8; ++u) {
    _Float16 h = (_Float16)v[u];
    hi[u] = h;
    lo[u] = (_Float16)(v[u] - (float)h);
  }
}

__device__ __forceinline__ void gload_lds16(const void* g, void* l) {
  __builtin_amdgcn_global_load_lds(
      (const __attribute__((address_space(1))) unsigned int*)g,
      (__attribute__((address_space(3))) unsigned int*)l, 16, 0, 0);
}

// ---------------- code norms + counter zeroing ----------------
__global__ __launch_bounds__(64) void vq_norms(const float* __restrict__ c0,
                                               const float* __restrict__ c1,
                                               const float* __restrict__ c2,
                                               float* __restrict__ en,
                                               int* __restrict__ counts) {
  if (blockIdx.x == 0 && threadIdx.x < 4) counts[threadIdx.x] = 0;
  const int row = blockIdx.x;  // 0..767
  const float* cb = (row < 256) ? c0 : ((row < 512) ? c1 : c2);
  const int n = row & 255;
  const int lane = threadIdx.x;
  const float* r = cb + (size_t)n * D_MODEL;
  float s = 0.f;
  for (int c = lane; c < D_MODEL; c += 64) s = fmaf(r[c], r[c], s);
  for (int m = 1; m < 64; m <<= 1) s += __shfl_xor(s, m, 64);
  if (lane == 0) en[row] = s;
}

// ---------------- precompute split codebook, fragment-linear ----------------
__global__ __launch_bounds__(256) void vq_split_cb(const float* __restrict__ c0,
                                                   const float* __restrict__ c1,
                                                   const float* __restrict__ c2,
                                                   half8* __restrict__ bh,
                                                   half8* __restrict__ bl) {
  const int t = blockIdx.x * 256 + threadIdx.x;    // 0..36863
  const int lvl = t / 12288;
  const int rem = t - lvl * 12288;
  const int kt = rem >> 10;
  const int f = (rem >> 6) & 15;
  const int lane = rem & 63;
  const int code = (f >> 1) * 32 + (lane & 31);
  const int k0 = kt * 32 + (f & 1) * 16 + (lane >> 5) * 8;
  const float* cb = (lvl == 0) ? c0 : ((lvl == 1) ? c1 : c2);
  const float4 a = ld4(cb + code * D_MODEL + k0);
  const float4 b = ld4(cb + code * D_MODEL + k0 + 4);
  half8 hv, lv;
  cvt8(a, b, hv, lv);
  bh[t] = hv;
  bl[t] = lv;
}

// ---------------- fused main VQ kernel, all 3 levels, 2-phase pipelined ----------------
// 4608 blocks (XCD-swizzled), 256 threads = 4 waves (2M x 2N).
// BM=64 rows x 256 codes, BK=32. Double-buffered A (2x8KB) + B (2x32KB) = 80KB LDS.
// Per K-step: barrier#1 with COUNTED vmcnt(10) (next tile's 2 A-loads + 8 B-gloads
// stay in flight) before MFMA; plain barrier#2 AFTER MFMA so next iteration's
// writes into buf[cur] cannot race slow waves' MFMA reads (round-6 bug fix).
__global__ __launch_bounds__(256) void vq_mfma_all(
    const float* __restrict__ l0, const float* __restrict__ l1,
    const float* __restrict__ l2, const float* __restrict__ c0,
    const float* __restrict__ c1, const float* __restrict__ c2,
    const float* __restrict__ en_all,
    const half8* __restrict__ bh_pre, const half8* __restrict__ bl_pre,
    float* __restrict__ out, float* __restrict__ dmin_all,
    float* __restrict__ xn_all,
    int* __restrict__ list0, int* __restrict__ list1, int* __restrict__ list2,
    int* __restrict__ counts) {
  __shared__ __align__(16) unsigned char smem[81920];
  // K-loop layout (c = buffer 0/1):
  //   Ah[c]: c*8192 .. +4096 ; Al[c]: c*8192+4096 .. +4096
  //   Bh[c]: 16384 + c*32768 .. +16384 ; Bl[c]: +16384
  // post-K-loop aliases (first touched after the final K-loop barrier + MFMA):
  float*  scanbuf = (float*)smem;           //     0..32768  [32][256]
  float4* red     = (float4*)(smem + 32768);// 32768..36864  [32][8]
  float*  en_s    = (float*)(smem + 36864); // 36864..37888  [256]
  float4* rowres  = (float4*)(smem + 37888);// 37888..38912  [64]
  float*  xnp     = (float*)(smem + 38912); // 38912..39936  [64][4]
  int*    idxs    = (int*)(smem + 39936);   // 39936..40192  [64]

  // ---- level decode with bijective XCD swizzle (4608 % 8 == 0) ----
  const int swz = (blockIdx.x & 7) * 576 + (blockIdx.x >> 3);
  int lvl, blk;
  if (swz < 512)       { lvl = 0; blk = swz; }
  else if (swz < 2560) { lvl = 1; blk = swz - 512; }
  else                 { lvl = 2; blk = swz - 2560; }
  const float* x  = (lvl == 0) ? l0 : ((lvl == 1) ? l1 : l2);
  const float* cb = (lvl == 0) ? c0 : ((lvl == 1) ? c1 : c2);
  const float* en = en_all + lvl * 256;
  const half8* bh = bh_pre + lvl * 12288;
  const half8* bl = bl_pre + lvl * 12288;
  const long ioff = (lvl == 0) ? 0 : ((lvl == 1) ? 32768 : 163840);
  float* out_idx = out + ioff;
  float* out_q   = out + ((lvl == 0) ? 294913L : ((lvl == 1) ? 12877825L : 63209473L));
  float* dmin_lvl = dmin_all + ioff;
  float* xn_lvl   = xn_all + ioff;
  int* list = (lvl == 0) ? list0 : ((lvl == 1) ? list1 : list2);
  int* cnt  = counts + lvl;

  const int tid = threadIdx.x;
  const int lane = tid & 63;
  const int w = tid >> 6, wm = w >> 1, wn = w & 1;
  const int c31 = lane & 31, h = lane >> 5;
  const long m0 = (long)blk * BM;

  const int amt = tid >> 7;            // A staging: m-tile
  const int akc = (tid >> 6) & 1;      //            k-chunk
  const float* ap = x + (m0 + amt * 32 + c31) * (long)D_MODEL + akc * 16 + h * 8;
  const int aidx = (amt * 2 + akc) * 64 + lane;

  f32x16 acc[4];
#pragma unroll
  for (int n = 0; n < 4; ++n)
#pragma unroll
    for (int i = 0; i < 16; ++i) acc[n][i] = 0.f;

  float xn_part = 0.f;
  float4 ra[2][2];

  // ---- prologue: issue A(0) register loads, then B(0) gloads -> buf0 ----
  ra[0][0] = ld4(ap + 0);
  ra[0][1] = ld4(ap + 4);
#pragma unroll
  for (int r = 0; r < 4; ++r) {
    const int f = r * 4 + w;
    const size_t gi = (size_t)(f * 64 + lane);
    gload_lds16(bh + gi, (void*)(smem + 16384 + f * 1024));
    gload_lds16(bl + gi, (void*)(smem + 16384 + 16384 + f * 1024));
  }

#pragma unroll
  for (int kt = 0; kt < NKT; ++kt) {
    const int cur = kt & 1;
    const int nxt = cur ^ 1;
    // ---- stage phase: A(kt+1) reg loads FIRST, then B(kt+1) -> buf[nxt] ----
    if (kt + 1 < NKT) {
      const int ko = (kt + 1) * 32;
      ra[nxt][0] = ld4(ap + ko);
      ra[nxt][1] = ld4(ap + ko + 4);
#pragma unroll
      for (int r = 0; r < 4; ++r) {
        const int f = r * 4 + w;
        const size_t gi = (size_t)(kt + 1) * 1024 + (size_t)(f * 64 + lane);
        gload_lds16(bh + gi, (void*)(smem + 16384 + nxt * 32768 + f * 1024));
        gload_lds16(bl + gi, (void*)(smem + 16384 + nxt * 32768 + 16384 + f * 1024));
      }
    }
    // ---- convert A(kt) + norm partial, ds_write into A buf[cur] ----
    {
      const float4 a0 = ra[cur][0], a1 = ra[cur][1];
      half8 hv, lv;
      cvt8(a0, a1, hv, lv);
      xn_part = fmaf(a0.x, a0.x, xn_part); xn_part = fmaf(a0.y, a0.y, xn_part);
      xn_part = fmaf(a0.z, a0.z, xn_part); xn_part = fmaf(a0.w, a0.w, xn_part);
      xn_part = fmaf(a1.x, a1.x, xn_part); xn_part = fmaf(a1.y, a1.y, xn_part);
      xn_part = fmaf(a1.z, a1.z, xn_part); xn_part = fmaf(a1.w, a1.w, xn_part);
      ((half8*)(smem + cur * 8192))[aidx] = hv;
      ((half8*)(smem + cur * 8192 + 4096))[aidx] = lv;
    }
    // ---- barrier#1: B(kt)+A(kt) visible; 10 next-tile loads stay in flight ----
    if (kt + 1 < NKT) {
      asm volatile("s_waitcnt vmcnt(10) lgkmcnt(0)" ::: "memory");
    } else {
      asm volatile("s_waitcnt vmcnt(0) lgkmcnt(0)" ::: "memory");
    }
    __builtin_amdgcn_s_barrier();
    // ---- MFMA phase on buf[cur] ----
    {
      const half8* Ah = (const half8*)(smem + cur * 8192);
      const half8* Al = (const half8*)(smem + cur * 8192 + 4096);
      const half8* Bh = (const half8*)(smem + 16384 + cur * 32768);
      const half8* Bl = (const half8*)(smem + 16384 + cur * 32768 + 16384);
      half8 ah0 = Ah[(wm * 2 + 0) * 64 + lane];
      half8 al0 = Al[(wm * 2 + 0) * 64 + lane];
      half8 ah1 = Ah[(wm * 2 + 1) * 64 + lane];
      half8 al1 = Al[(wm * 2 + 1) * 64 + lane];
#pragma unroll
      for (int n = 0; n < 4; ++n) {
        const int nt = wn * 4 + n;
        half8 bh0 = Bh[(nt * 2 + 0) * 64 + lane], bl0 = Bl[(nt * 2 + 0) * 64 + lane];
        half8 bh1 = Bh[(nt * 2 + 1) * 64 + lane], bl1 = Bl[(nt * 2 + 1) * 64 + lane];
        // 6-term split: hi*hi + hi*lo + lo*hi (lo*lo dropped; rescue covers)
        acc[n] = __builtin_amdgcn_mfma_f32_32x32x16_f16(ah0, bh0, acc[n], 0, 0, 0);
        acc[n] = __builtin_amdgcn_mfma_f32_32x32x16_f16(ah0, bl0, acc[n], 0, 0, 0);
        acc[n] = __builtin_amdgcn_mfma_f32_32x32x16_f16(al0, bh0, acc[n], 0, 0, 0);
        acc[n] = __builtin_amdgcn_mfma_f32_32x32x16_f16(ah1, bh1, acc[n], 0, 0, 0);
        acc[n] = __builtin_amdgcn_mfma_f32_32x32x16_f16(ah1, bl1, acc[n], 0, 0, 0);
        acc[n] = __builtin_amdgcn_mfma_f32_32x32x16_f16(al1, bh1, acc[n], 0, 0, 0);
      }
    }
    // ---- barrier#2 (round-6 fix): protect buf[cur] reads from iter kt+1's
    //      writes (B gloads + A ds_writes target buf[cur] next iteration).
    if (kt + 1 < NKT) __builtin_amdgcn_s_barrier();
    // (after kt=11: epilogue writes only touch Bbuf0, last read at kt=10 and
    //  protected by barrier#2(10); scanbuf written after __syncthreads below)
  }

  // post-loop: populate aliased epilogue structures (Bbuf0 region, safe)
  xnp[(amt * 32 + c31) * 4 + (akc * 2 + h)] = xn_part;
  en_s[tid] = en[tid];

  // ---- epilogue: approx top-2 per row via LDS scan, 2 batches of 32 rows ----
#pragma unroll 1
  for (int b = 0; b < 2; ++b) {
    __syncthreads();
    if (wm == b) {
#pragma unroll
      for (int n = 0; n < 4; ++n) {
        const int colbase = wn * 128 + n * 32 + c31;
#pragma unroll
        for (int rr = 0; rr < 16; ++rr) {
          const int row_b = (rr & 3) + ((rr >> 2) << 3) + (h << 2);
          const int p = colbase ^ ((row_b & 3) << 3);
          scanbuf[row_b * 256 + p] = fmaf(-2.f, acc[n][rr], en_s[colbase]);
        }
      }
    }
    __syncthreads();
    {
      const int srow = tid >> 3, chunk = tid & 7;
      float b1 = 1e30f, b2 = 1e30f; int i1 = 0, i2 = 0;
#pragma unroll
      for (int u = 0; u < 32; ++u) {
        const int col = chunk + u * 8;
        const float d = scanbuf[srow * 256 + (col ^ ((srow & 3) << 3))];
        if (d < b1) { b2 = b1; i2 = i1; b1 = d; i1 = col; }
        else if (d < b2) { b2 = d; i2 = col; }
      }
      red[srow * 8 + chunk] = make_float4(b1, __int_as_float(i1), b2, __int_as_float(i2));
    }
    __syncthreads();
    if (tid < 32) {
      float4 q = red[tid * 8 + 0];
      float fb1 = q.x, fb2 = q.z;
      int fi1 = __float_as_int(q.y), fi2 = __float_as_int(q.w);
#pragma unroll
      for (int c = 1; c < 8; ++c) {
        q = red[tid * 8 + c];
        const float c1 = q.x, c2 = q.z;
        const int j1 = __float_as_int(q.y), j2 = __float_as_int(q.w);
        if (c1 < fb1 || (c1 == fb1 && j1 < fi1)) {
          if (fb1 < c2 || (fb1 == c2 && fi1 < j2)) { fb2 = fb1; fi2 = fi1; }
          else { fb2 = c2; fi2 = j2; }
          fb1 = c1; fi1 = j1;
        } else if (c1 < fb2 || (c1 == fb2 && j1 < fi2)) { fb2 = c1; fi2 = j1; }
      }
      rowres[b * 32 + tid] = make_float4(fb1, __int_as_float(fi1), fb2, __int_as_float(fi2));
    }
  }
  __syncthreads();

  // ---- finalize: write approx results; flag + compact near-ties ----
  if (tid < BM) {
    const int m = tid;
    const float4 qv = rowres[m];
    const float fb1 = qv.x, fb2 = qv.z;
    const int fi1 = __float_as_int(qv.y);
    const float xn = (xnp[m * 4 + 0] + xnp[m * 4 + 1]) + (xnp[m * 4 + 2] + xnp[m * 4 + 3]);
    idxs[m] = fi1;
    out_idx[m0 + m] = (float)fi1;
    dmin_lvl[m0 + m] = xn + fb1;
    xn_lvl[m0 + m] = xn;
    const bool flg = (fb2 - fb1 < RTAU);
    const unsigned long long mask = __ballot(flg);
    const int nf = __popcll(mask);
    int base = 0;
    if (tid == 0 && nf) base = atomicAdd(cnt, nf);
    base = __shfl(base, 0, 64);
    if (flg) {
      const int pos = __popcll(mask & ((1ull << tid) - 1ull));
      list[base + pos] = (int)(m0 + m);
    }
  }
  __syncthreads();

  // q = codebook[idx] (provisional for flagged rows; rescue overwrites)
  float* qb = out_q + m0 * (long)D_MODEL;
  for (int g = tid; g < BM * NSEG; g += 256) {
    const int m = g / NSEG;
    const int seg = g - m * NSEG;
    *(float4*)(qb + m * (long)D_MODEL + seg * 4) = ld4(cb + (long)idxs[m] * D_MODEL + seg * 4);
  }
}

// ---------------- fused exact rescue, all 3 levels ----------------
__global__ __launch_bounds__(256) void vq_rescue_all(
    const float* __restrict__ l0, const float* __restrict__ l1,
    const float* __restrict__ l2, const float* __restrict__ c0,
    const float* __restrict__ c1, const float* __restrict__ c2,
    const float* __restrict__ en_all,
    const int* __restrict__ list0, const int* __restrict__ list1,
    const int* __restrict__ list2, const int* __restrict__ counts,
    float* __restrict__ out, float* __restrict__ dmin_all,
    const float* __restrict__ xn_all) {
  __shared__ float xs[8][D_MODEL];
  __shared__ int rows_s[8];
  __shared__ float xns_s[8];
  __shared__ float dall[8][256];
  __shared__ int best_s[8];

  const int lvl = blockIdx.x >> 7;          // 128 blocks per level
  const int sb  = blockIdx.x & 127;
  const float* x  = (lvl == 0) ? l0 : ((lvl == 1) ? l1 : l2);
  const float* cb = (lvl == 0) ? c0 : ((lvl == 1) ? c1 : c2);
  const float* en_lvl = en_all + lvl * 256;
  const int* list = (lvl == 0) ? list0 : ((lvl == 1) ? list1 : list2);
  const long ioff = (lvl == 0) ? 0 : ((lvl == 1) ? 32768 : 163840);
  float* out_idx = out + ioff;
  float* out_q   = out + ((lvl == 0) ? 294913L : ((lvl == 1) ? 12877825L : 63209473L));
  float* dmin_lvl = dmin_all + ioff;
  const float* xn_lvl = xn_all + ioff;

  const int tid = threadIdx.x;
  const int count = counts[lvl];
  const int nch = (count + 7) >> 3;
  const float en_t = en_lvl[tid];
  const int w = tid >> 6, lane = tid & 63;
  const float* crow = cb + (long)tid * D_MODEL;

  for (int c = sb; c < nch; c += 128) {
    const int base = c << 3;
    const int R = min(8, count - base);
    if (tid < 8) {
      const int j = min(tid, R - 1);
      const int r = list[base + j];
      rows_s[tid] = r;
      xns_s[tid] = xn_lvl[r];
    }
    __syncthreads();
#pragma unroll
    for (int r = 0; r < 8; ++r)
      if (tid < NSEG) *(float4*)&xs[r][tid * 4] = ld4(x + (long)rows_s[r] * D_MODEL + tid * 4);
    __syncthreads();

    float acc[8] = {0.f, 0.f, 0.f, 0.f, 0.f, 0.f, 0.f, 0.f};
    for (int seg = 0; seg < NSEG; ++seg) {     // exact ascending-k fp32 chain
      const float4 e = ld4(crow + seg * 4);
#pragma unroll
      for (int r = 0; r < 8; ++r) {
        const float4 xv = *(const float4*)&xs[r][seg * 4];
        acc[r] = fmaf(xv.x, e.x, acc[r]);
        acc[r] = fmaf(xv.y, e.y, acc[r]);
        acc[r] = fmaf(xv.z, e.z, acc[r]);
        acc[r] = fmaf(xv.w, e.w, acc[r]);
      }
    }
#pragma unroll
    for (int r = 0; r < 8; ++r)
      dall[r][tid] = fmaf(-2.f, acc[r], xns_s[r]) + en_t;
    __syncthreads();

#pragma unroll
    for (int rr = 0; rr < 2; ++rr) {
      const int r = w + rr * 4;
      if (r < R) {
        float best = dall[r][lane]; int bidx = lane;
#pragma unroll
        for (int u = 1; u < 4; ++u) {
          const int code = lane + u * 64;
          const float d = dall[r][code];
          if (d < best) { best = d; bidx = code; }
        }
        for (int mm = 1; mm < 64; mm <<= 1) {
          const float ov = __shfl_xor(best, mm, 64);
          const int oi = __shfl_xor(bidx, mm, 64);
          if (ov < best || (ov == best && oi < bidx)) { best = ov; bidx = oi; }
        }
        if (lane == 0) {
          const int row = rows_s[r];
          out_idx[row] = (float)bidx;
          dmin_lvl[row] = best;
          best_s[r] = bidx;
        }
      }
    }
    __syncthreads();
#pragma unroll
    for (int r = 0; r < 8; ++r)
      if (r < R && tid < NSEG)
        *(float4*)(out_q + (long)rows_s[r] * D_MODEL + tid * 4) =
            ld4(cb + (long)best_s[r] * D_MODEL + tid * 4);
    __syncthreads();
  }
}

// ---------------- deterministic loss reduce (after rescue) ----------------
__global__ __launch_bounds__(256) void loss_stage1(const float* __restrict__ dmin,
                                                   double* __restrict__ lp) {
  const int b = blockIdx.x;           // 576 blocks x 512 rows
  const int tid = threadIdx.x;
  const long r0 = (long)b * 512;
  __shared__ double sh[256];
  sh[tid] = (double)dmin[r0 + tid] + (double)dmin[r0 + 256 + tid];
  __syncthreads();
  for (int st = 128; st > 0; st >>= 1) {
    if (tid < st) sh[tid] += sh[tid + st];
    __syncthreads();
  }
  if (tid == 0) {
    double scale;
    if (b < 64)       scale = 0.05 / (32768.0 * 384.0);
    else if (b < 320) scale = 0.25 / (131072.0 * 384.0);
    else              scale = 0.60 / (131072.0 * 384.0);
    lp[b] = sh[0] * scale;
  }
}

__global__ __launch_bounds__(256) void loss_stage2(const double* __restrict__ lp,
                                                   float* __restrict__ out_loss) {
  const int tid = threadIdx.x;
  __shared__ double sh[256];
  sh[tid] = lp[tid] + lp[tid + 256] + ((tid < 64) ? lp[tid + 512] : 0.0);
  __syncthreads();
  for (int st = 128; st > 0; st >>= 1) {
    if (tid < st) sh[tid] += sh[tid + st];
    __syncthreads();
  }
  if (tid == 0) out_loss[0] = (float)sh[0];
}

extern "C" void kernel_launch(void* const* d_in, const int* in_sizes, int n_in,
                              void* d_out, int out_size, void* d_ws, size_t ws_size,
                              hipStream_t stream) {
  const float* l0 = (const float*)d_in[0];
  const float* l1 = (const float*)d_in[1];
  const float* l2 = (const float*)d_in[2];
  const float* c0 = (const float*)d_in[3];
  const float* c1 = (const float*)d_in[4];
  const float* c2 = (const float*)d_in[5];
  float* out = (float*)d_out;

  float* wsf = (float*)d_ws;
  int*   counts   = (int*)wsf;               // 4 ints
  float* en       = wsf + 4;                 // 768
  float* dmin_all = wsf + 772;               // 294912
  float* xn_all   = wsf + 295684;            // 294912
  int*   list0    = (int*)(wsf + 590596);    // cap 32768
  int*   list1    = (int*)(wsf + 623364);    // cap 131072
  int*   list2    = (int*)(wsf + 754436);    // cap 131072
  double* lp      = (double*)(wsf + 885508); // 576 doubles
  half8* bh_pre   = (half8*)(wsf + 886660);  // 36864 half8 (16B-aligned)
  half8* bl_pre   = (half8*)(wsf + 1034116); // 36864 half8

  vq_norms<<<768, 64, 0, stream>>>(c0, c1, c2, en, counts);
  vq_split_cb<<<144, 256, 0, stream>>>(c0, c1, c2, bh_pre, bl_pre);

  vq_mfma_all<<<4608, 256, 0, stream>>>(l0, l1, l2, c0, c1, c2, en,
                                        bh_pre, bl_pre, out,
                                        dmin_all, xn_all,
                                        list0, list1, list2, counts);

  vq_rescue_all<<<384, 256, 0, stream>>>(l0, l1, l2, c0, c1, c2, en,
                                         list0, list1, list2, counts,
                                         out, dmin_all, xn_all);

  loss_stage1<<<576, 256, 0, stream>>>(dmin_all, lp);
  loss_stage2<<<1, 256, 0, stream>>>(lp, out + 294912);
}